// Round 11
// baseline (444.074 us; speedup 1.0000x reference)
//
#include <hip/hip_runtime.h>

// CodebookQuantizer: out[q] = softmax_k( (2*h[q].cb[k] - |cb[k]|^2) / T ) @ cb
// B*Q = 16384, D = 512, K = 8192, T = 0.1. Output fp32 (z_e forward value).
//
// fp8-e4m3 MFMA scan (16x16x32_fp8_fp8); one wave owns 64 q rows (hf = 128
// VGPR). K2 needs ~230 VGPR live -> __launch_bounds__(256,1) (cap 512).
// Round-10 failure mode: default/over-tight caps made the allocator stop at
// 128 VGPR and spill hf to scratch (WRITE_SIZE 164 MB/dispatch, MfmaUtil 0.4%).
// Occupancy is LDS-bound at 2 blocks/CU anyway; registers are free to use.
// K1: codebook fp32 -> fp8, frag-permuted + XOR-swizzled units, + esq*SC_ESQ.
// K2: 512 blocks = 64 q-tiles x 8 octants (512KB slice L2-pinned per XCD);
//     256 thr = 4 waves x 64 q. Approx logits; per (row,octant) sub-list:
//     8 protected slots (top-2 per owning lane, register-tracked, main loop
//     only) + 8-slot ring. Weight-relevant codes are always in-lane top-2.
// K3: merge 8 sub-lists, dedup, prune at max-360 (6-sigma fp8 noise margin),
//     exact fp32 logits + online softmax + gather.

typedef float          f32x4 __attribute__((ext_vector_type(4)));
typedef unsigned long  u64x2 __attribute__((ext_vector_type(2)));

#define BQ      256
#define KC      64
#define DD      512
#define NCODES  8192
#define NOCT    8
#define OCODES  (NCODES / NOCT)   // 1024
#define NCHUNK  (OCODES / KC)     // 16
#define NSUB    8
#define CAPS    16
#define NPROT   8
#define TH2     170.0f            // scan append threshold (log2 units)
#define PRUNE   360.0f            // merge prune threshold (log2 units, 6-sigma)

#define SC_CROSS 28.853900817779268f   // 2/T*log2(e)
#define SC_ESQ   14.426950408889634f   // 1/T*log2(e)

#define SZ_CBF8  ((size_t)NCODES * DD)              // 4 MB
#define SZ_ESQ   ((size_t)NCODES * 4)               // 32 KB
#define SZ_WLIST ((size_t)16384 * NSUB * CAPS * 4)  // 8.4 MB
#define SZ_WCNT  ((size_t)16384 * NSUB * 4)         // 512 KB

static __device__ __forceinline__ unsigned short f2bf(float x) {
    unsigned int u = __float_as_uint(x);
    u += 0x7fffu + ((u >> 16) & 1u);
    return (unsigned short)(u >> 16);
}
static __device__ __forceinline__ unsigned int packE(float L, int code) {
    return ((unsigned int)f2bf(L) << 16) | (unsigned int)code;
}
// word-select must be a literal constant -> template parameter
template <bool HI>
static __device__ __forceinline__ unsigned int pk8(float a, float b, unsigned int old) {
    return __builtin_amdgcn_cvt_pk_fp8_f32(a, b, (int)old, HI);
}
static __device__ __forceinline__ f32x4 mfma8(unsigned long a, unsigned long b, f32x4 c) {
    return __builtin_amdgcn_mfma_f32_16x16x32_fp8_fp8((long)a, (long)b, c, 0, 0, 0);
}
static __device__ __forceinline__ void gload_lds16(const void* g, void* l) {
    __builtin_amdgcn_global_load_lds(
        (const __attribute__((address_space(1))) unsigned int*)g,
        (__attribute__((address_space(3))) unsigned int*)l, 16, 0, 0);
}
static __device__ __forceinline__ void gload_lds4(const void* g, void* l) {
    __builtin_amdgcn_global_load_lds(
        (const __attribute__((address_space(1))) unsigned int*)g,
        (__attribute__((address_space(3))) unsigned int*)l, 4, 0, 0);
}

// ---- K1: codebook -> fp8 frag-permuted units + pre-scaled e_sq ----
// Row r (512 B) = 32 units of 16 B. Logical unit u = p*4+g holds ksteps
// (2p,2p+1) for lane-group g: bytes 0..7 = k(64p+8g..+7), 8..15 = +32.
// Stored at position (u ^ (r&7)) for bank spread; K2 reads with same XOR.
__global__ __launch_bounds__(256)
void vq_convert_cb(const float* __restrict__ cb,
                   unsigned char* __restrict__ cbf8,
                   float* __restrict__ esqp)
{
    const int r = blockIdx.x * 8 + (threadIdx.x >> 5);
    const int u = threadIdx.x & 31;
    const int p = u >> 2, g = u & 3;
    const int k0 = p * 64 + g * 8;
    const float* src = cb + (size_t)r * DD;
    float4 a0 = *reinterpret_cast<const float4*>(src + k0);
    float4 a1 = *reinterpret_cast<const float4*>(src + k0 + 4);
    float4 b0 = *reinterpret_cast<const float4*>(src + k0 + 32);
    float4 b1 = *reinterpret_cast<const float4*>(src + k0 + 36);
    unsigned int w0 = pk8<false>(a0.x, a0.y, 0); w0 = pk8<true>(a0.z, a0.w, w0);
    unsigned int w1 = pk8<false>(a1.x, a1.y, 0); w1 = pk8<true>(a1.z, a1.w, w1);
    unsigned int w2 = pk8<false>(b0.x, b0.y, 0); w2 = pk8<true>(b0.z, b0.w, w2);
    unsigned int w3 = pk8<false>(b1.x, b1.y, 0); w3 = pk8<true>(b1.z, b1.w, w3);
    float s2 = a0.x*a0.x + a0.y*a0.y + a0.z*a0.z + a0.w*a0.w
             + a1.x*a1.x + a1.y*a1.y + a1.z*a1.z + a1.w*a1.w
             + b0.x*b0.x + b0.y*b0.y + b0.z*b0.z + b0.w*b0.w
             + b1.x*b1.x + b1.y*b1.y + b1.z*b1.z + b1.w*b1.w;
#pragma unroll
    for (int off = 16; off > 0; off >>= 1) s2 += __shfl_xor(s2, off);
    if (u == 0) esqp[r] = s2 * SC_ESQ;
    uint4 o = {w0, w1, w2, w3};
    *reinterpret_cast<uint4*>(cbf8 + (size_t)r * DD + (u ^ (r & 7)) * 16) = o;
}

// ---- K2: fp8 scan, one octant x 256 q rows per block ----
// launch_bounds(256,1): VGPR cap 512 -> no spill (hf alone is 128 VGPR).
// Occupancy is LDS-bound (67 KB -> 2 blocks/CU) regardless of VGPR count.
__global__ __launch_bounds__(256, 1)
void vq_scan_kernel(const float* __restrict__ h,
                    const unsigned char* __restrict__ cbf8,
                    const float* __restrict__ esqp,
                    unsigned int* __restrict__ wlist,
                    unsigned int* __restrict__ wcnt)
{
    __shared__ __align__(16) unsigned char sC[2][KC * DD];   // 64 KB dbuf
    __shared__ __align__(16) float sEsq[2][KC];
    __shared__ int sCnt[BQ];

    const int tid  = threadIdx.x;
    const int w    = tid >> 6;          // wave 0..3, owns q [w*64, w*64+64)
    const int lane = tid & 63;
    const int c16  = lane & 15;
    const int ub   = lane >> 4;
    const int oct  = blockIdx.x & 7;    // constant per XCD -> slice L2-pinned
    const int qt   = blockIdx.x >> 3;
    const int qb   = qt * BQ;
    const int g0   = oct * OCODES;

    if (tid < BQ) sCnt[tid] = NPROT;

    // ---- inline h -> fp8 B-fragments: hf[cg][s], cg = q col-group ----
    unsigned long hf[4][16];
#pragma unroll
    for (int cg = 0; cg < 4; ++cg) {
        const size_t qrow = (size_t)(qb + w * 64 + cg * 16 + c16);
#pragma unroll
        for (int s = 0; s < 16; ++s) {
            const float* src = h + qrow * DD + s * 32 + ub * 8;
            float4 x = *reinterpret_cast<const float4*>(src);
            float4 y = *reinterpret_cast<const float4*>(src + 4);
            unsigned int lo = pk8<false>(x.x, x.y, 0); lo = pk8<true>(x.z, x.w, lo);
            unsigned int hi = pk8<false>(y.x, y.y, 0); hi = pk8<true>(y.z, y.w, hi);
            hf[cg][s] = (unsigned long)lo | ((unsigned long)hi << 32);
        }
    }

    float mrun[4] = {-1e38f, -1e38f, -1e38f, -1e38f};
    float b1L[4]  = {-1e38f, -1e38f, -1e38f, -1e38f};
    float b2L[4]  = {-1e38f, -1e38f, -1e38f, -1e38f};
    int   b1C[4]  = {0, 0, 0, 0};
    int   b2C[4]  = {0, 0, 0, 0};

    const int sz = c16 & 7;

    auto stage = [&](int b, int ct) {
        const unsigned char* gc = cbf8 + ((size_t)g0 + (size_t)ct * KC) * DD;
#pragma unroll
        for (int r = 0; r < 8; ++r)
            gload_lds16(gc + r * 4096 + tid * 16, &sC[b][0] + r * 4096 + tid * 16);
        if (w == 0)
            gload_lds4((const char*)(esqp + g0 + ct * KC) + lane * 4,
                       (char*)&sEsq[b][0] + lane * 4);
    };

    // track only in the main loop (prepass re-scans chunk 0: double-tracking
    // would duplicate chunk-0 tops into b2 -- the round-6 bug).
    auto scan_chunk = [&](int cur, int gbase, bool append, bool track) {
        float thr[4], ml[4];
#pragma unroll
        for (int cg = 0; cg < 4; ++cg) { thr[cg] = mrun[cg] - TH2; ml[cg] = -1e38f; }
#pragma unroll 1
        for (int ct = 0; ct < 4; ++ct) {
            const int crow = ct * 16 + c16;
            const unsigned char* base = &sC[cur][crow * DD];
            u64x2 a[8];
#pragma unroll
            for (int p = 0; p < 8; ++p)
                a[p] = *reinterpret_cast<const u64x2*>(base + ((p * 4 + ub) ^ sz) * 16);
            f32x4 ep = *reinterpret_cast<const f32x4*>(&sEsq[cur][ct * 16 + ub * 4]);
#pragma unroll
            for (int cg = 0; cg < 4; ++cg) {
                f32x4 acc = {0.f, 0.f, 0.f, 0.f};
#pragma unroll
                for (int p = 0; p < 8; ++p) {
                    acc = mfma8(a[p].x, hf[cg][2 * p],     acc);
                    acc = mfma8(a[p].y, hf[cg][2 * p + 1], acc);
                }
                float Lv[4];
#pragma unroll
                for (int r = 0; r < 4; ++r) Lv[r] = fmaf(acc[r], SC_CROSS, -ep[r]);
                if (track) {
#pragma unroll
                    for (int r = 0; r < 4; ++r) {
                        const int cd = gbase + ct * 16 + ub * 4 + r;
                        if (Lv[r] > b1L[cg])      { b2L[cg] = b1L[cg]; b2C[cg] = b1C[cg];
                                                    b1L[cg] = Lv[r];   b1C[cg] = cd; }
                        else if (Lv[r] > b2L[cg]) { b2L[cg] = Lv[r];   b2C[cg] = cd; }
                    }
                }
                if (append) {
                    if (Lv[0] > thr[cg] || Lv[1] > thr[cg] ||
                        Lv[2] > thr[cg] || Lv[3] > thr[cg]) {
                        const int rowloc = w * 64 + cg * 16 + c16;
                        const size_t lb = ((size_t)(qb + rowloc) * NSUB + oct) * CAPS;
#pragma unroll
                        for (int r = 0; r < 4; ++r)
                            if (Lv[r] > thr[cg]) {
                                int idx  = atomicAdd(&sCnt[rowloc], 1);
                                int slot = idx < CAPS ? idx
                                         : NPROT + ((idx - NPROT) & (NPROT - 1));
                                wlist[lb + slot] = packE(Lv[r], gbase + ct * 16 + ub * 4 + r);
                            }
                    }
                }
                float m4 = fmaxf(fmaxf(Lv[0], Lv[1]), fmaxf(Lv[2], Lv[3]));
                ml[cg] = fmaxf(ml[cg], m4);
            }
        }
#pragma unroll
        for (int cg = 0; cg < 4; ++cg) {
            float m = ml[cg];
            m = fmaxf(m, __shfl_xor(m, 16));
            m = fmaxf(m, __shfl_xor(m, 32));
            mrun[cg] = fmaxf(mrun[cg], m);
        }
    };

    // prologue: stage chunk 0; prime running max (no append, no tracking)
    stage(0, 0);
    __syncthreads();
    scan_chunk(0, g0, false, false);

    int cur = 0;
    for (int t = 0; t < NCHUNK; ++t) {
        if (t + 1 < NCHUNK) stage(cur ^ 1, t + 1);
        scan_chunk(cur, g0 + t * KC, true, true);
        __syncthreads();
        cur ^= 1;
    }

    // protected slots: per cg row, owning lane ub writes its top-2
#pragma unroll
    for (int cg = 0; cg < 4; ++cg) {
        const int rowloc = w * 64 + cg * 16 + c16;
        const size_t lb = ((size_t)(qb + rowloc) * NSUB + oct) * CAPS;
        wlist[lb + ub * 2]     = packE(b1L[cg], b1C[cg]);
        wlist[lb + ub * 2 + 1] = packE(b2L[cg], b2C[cg]);
    }
    if (tid < BQ) wcnt[(size_t)(qb + tid) * NSUB + oct] = (unsigned)sCnt[tid];
}

// ---- K3: merge sub-lists, dedup, prune, exact fp32 softmax gather ----
__global__ __launch_bounds__(512)
void vq_merge_kernel(const float* __restrict__ h,
                     const float* __restrict__ cb,
                     const unsigned int* __restrict__ wlist,
                     const unsigned int* __restrict__ wcnt,
                     float* __restrict__ out)
{
    const int w    = threadIdx.x >> 6;
    const int lane = threadIdx.x & 63;
    const int qg   = blockIdx.x * 8 + w;

    const int sl = lane >> 3;           // sub-list (octant) 0..7
    const int s0 = (lane & 7) * 2;      // slot pair
    const size_t base = ((size_t)qg * NSUB + sl) * CAPS;
    const unsigned cnt   = wcnt[(size_t)qg * NSUB + sl];
    const unsigned limit = cnt < (unsigned)CAPS ? cnt : (unsigned)CAPS;

    uint2 e2 = *reinterpret_cast<const uint2*>(&wlist[base + s0]);
    int   code0 = e2.x & 0xFFFF, code1 = e2.y & 0xFFFF;
    float L0 = __uint_as_float(e2.x & 0xFFFF0000u);
    float L1 = __uint_as_float(e2.y & 0xFFFF0000u);
    bool v0 = (unsigned)s0 < limit;
    bool v1 = (unsigned)(s0 + 1) < limit;
    {
        uint4 p0 = *reinterpret_cast<const uint4*>(&wlist[base]);
        uint4 p1 = *reinterpret_cast<const uint4*>(&wlist[base + 4]);
        const unsigned pc[8] = {p0.x & 0xFFFFu, p0.y & 0xFFFFu, p0.z & 0xFFFFu, p0.w & 0xFFFFu,
                                p1.x & 0xFFFFu, p1.y & 0xFFFFu, p1.z & 0xFFFFu, p1.w & 0xFFFFu};
        const int lim0 = (s0 >= NPROT) ? 8 : s0;
        bool d0 = false, d1 = false;
#pragma unroll
        for (int j = 0; j < 8; ++j) {
            d0 |= (j < lim0) && ((unsigned)code0 == pc[j]);
            d1 |= (j < lim0) && ((unsigned)code1 == pc[j]);
        }
        d1 |= (code1 == code0) && (s0 < NPROT);
        v0 &= !d0; v1 &= !d1;
    }

    float m = fmaxf(v0 ? L0 : -1e38f, v1 ? L1 : -1e38f);
#pragma unroll
    for (int off = 1; off < 64; off <<= 1) m = fmaxf(m, __shfl_xor(m, off));
    const float thr = m - PRUNE;
    unsigned long long mask0 = __ballot(v0 && L0 > thr);
    unsigned long long mask1 = __ballot(v1 && L1 > thr);

    float hreg[8];
    const float* hp = h + (size_t)qg * DD + lane * 8;
#pragma unroll
    for (int j = 0; j < 8; ++j) hreg[j] = hp[j];

    float Mex = -1e38f, lsum = 0.f;
    float acc[8] = {0.f,0.f,0.f,0.f,0.f,0.f,0.f,0.f};

    auto process = [&](unsigned long long mask, int codev) {
#pragma unroll 1
        while (mask) {
            const int s = __builtin_ctzll(mask);
            mask &= mask - 1;
            const int code = __shfl(codev, s);
            const float* cp = cb + (size_t)code * DD + lane * 8;
            float c[8];
            float dot = 0.f, s2 = 0.f;
#pragma unroll
            for (int j = 0; j < 8; ++j) {
                c[j] = cp[j];
                dot += hreg[j] * c[j];
                s2  += c[j] * c[j];
            }
#pragma unroll
            for (int off = 32; off > 0; off >>= 1) {
                dot += __shfl_xor(dot, off);
                s2  += __shfl_xor(s2,  off);
            }
            const float Lex = dot * SC_CROSS - s2 * SC_ESQ;   // exact log2-logit
            const float mn  = fmaxf(Mex, Lex);
            const float f   = exp2f(Mex - mn);
            const float wj  = exp2f(Lex - mn);
            lsum = lsum * f + wj;
#pragma unroll
            for (int j = 0; j < 8; ++j) acc[j] = acc[j] * f + wj * c[j];
            Mex = mn;
        }
    };
    process(mask0, code0);
    process(mask1, code1);

    const float inv = 1.0f / lsum;
    float* op = out + (size_t)qg * DD + lane * 8;
    float4 o0 = {acc[0]*inv, acc[1]*inv, acc[2]*inv, acc[3]*inv};
    float4 o1 = {acc[4]*inv, acc[5]*inv, acc[6]*inv, acc[7]*inv};
    *reinterpret_cast<float4*>(op)     = o0;
    *reinterpret_cast<float4*>(op + 4) = o1;
}

extern "C" void kernel_launch(void* const* d_in, const int* in_sizes, int n_in,
                              void* d_out, int out_size, void* d_ws, size_t ws_size,
                              hipStream_t stream) {
    const float* h  = (const float*)d_in[0];   // (16384, 512) fp32
    const float* cb = (const float*)d_in[1];   // (8192, 512) fp32
    float* out = (float*)d_out;                // (16384, 512) fp32

    // ws: cbf8 4MB | esqp 32KB | wlist 8.4MB | wcnt 512KB  (~12.9 MB)
    char* p = (char*)d_ws;
    unsigned char* cbf8 = (unsigned char*)p;  p += SZ_CBF8;
    float*         esqp = (float*)p;          p += SZ_ESQ;
    unsigned int*  wlist = (unsigned int*)p;  p += SZ_WLIST;
    unsigned int*  wcnt  = (unsigned int*)p;

    vq_convert_cb<<<dim3(NCODES / 8), dim3(256), 0, stream>>>(cb, cbf8, esqp);
    vq_scan_kernel<<<dim3(512), dim3(256), 0, stream>>>(h, cbf8, esqp, wlist, wcnt);
    vq_merge_kernel<<<dim3(16384 / 8), dim3(512), 0, stream>>>(h, cb, wlist, wcnt, out);
}

// Round 12
// 295.903 us; speedup vs baseline: 1.5007x; 1.5007x over previous
//
#include <hip/hip_runtime.h>

// CodebookQuantizer: out[q] = softmax_k( (2*h[q].cb[k] - |cb[k]|^2) / T ) @ cb
// B*Q = 16384, D = 512, K = 8192, T = 0.1. Output fp32 (z_e forward value).
//
// fp8-e4m3 MFMA scan. Register cliff (m69: waves/SIMD steps at VGPR 64/128/256):
//   r10: hf[4][16]=128 VGPR + cap 128 -> spilled (WRITE 164MB, MfmaUtil 0.4%)
//   r11: cap 512 -> 256 VGPR -> 1 wave/SIMD (Occ 12%) -> slower
// Fix: hf[2][16] (32 q/wave) = 64 VGPR, a[4] two-batch prefetch -> ~125 VGPR
// natural; launch_bounds(256,4) caps at 128. KC=32 -> 33KB LDS -> 4 blocks/CU
// -> 16 waves/CU (4/SIMD).
// K1: codebook fp32 -> fp8, frag-permuted + XOR-swizzled units, + esq*SC_ESQ.
// K2: 1024 blocks = 128 q-tiles x 8 octants (512KB slice L2-pinned per XCD);
//     256 thr = 4 waves x 32 q. Per (row,octant) sub-list: 8 protected slots
//     (top-2 per owning lane, register-tracked, main loop only) + 8-slot ring.
// K3: merge 8 sub-lists, dedup, prune at max-360 (6-sigma fp8 noise margin),
//     exact fp32 logits + online softmax + gather.

typedef float          f32x4 __attribute__((ext_vector_type(4)));
typedef unsigned long  u64x2 __attribute__((ext_vector_type(2)));

#define BQ      128               // q rows per block (4 waves x 32)
#define KC      32                // codebook rows per chunk
#define DD      512
#define NCODES  8192
#define NOCT    8
#define OCODES  (NCODES / NOCT)   // 1024
#define NCHUNK  (OCODES / KC)     // 32
#define NSUB    8
#define CAPS    16
#define NPROT   8
#define TH2     170.0f            // scan append threshold (log2 units)
#define PRUNE   360.0f            // merge prune threshold (log2 units, 6-sigma)

#define SC_CROSS 28.853900817779268f   // 2/T*log2(e)
#define SC_ESQ   14.426950408889634f   // 1/T*log2(e)

#define SZ_CBF8  ((size_t)NCODES * DD)              // 4 MB
#define SZ_ESQ   ((size_t)NCODES * 4)               // 32 KB
#define SZ_WLIST ((size_t)16384 * NSUB * CAPS * 4)  // 8.4 MB
#define SZ_WCNT  ((size_t)16384 * NSUB * 4)         // 512 KB

static __device__ __forceinline__ unsigned short f2bf(float x) {
    unsigned int u = __float_as_uint(x);
    u += 0x7fffu + ((u >> 16) & 1u);
    return (unsigned short)(u >> 16);
}
static __device__ __forceinline__ unsigned int packE(float L, int code) {
    return ((unsigned int)f2bf(L) << 16) | (unsigned int)code;
}
// word-select must be a literal constant -> template parameter
template <bool HI>
static __device__ __forceinline__ unsigned int pk8(float a, float b, unsigned int old) {
    return __builtin_amdgcn_cvt_pk_fp8_f32(a, b, (int)old, HI);
}
static __device__ __forceinline__ f32x4 mfma8(unsigned long a, unsigned long b, f32x4 c) {
    return __builtin_amdgcn_mfma_f32_16x16x32_fp8_fp8((long)a, (long)b, c, 0, 0, 0);
}
static __device__ __forceinline__ void gload_lds16(const void* g, void* l) {
    __builtin_amdgcn_global_load_lds(
        (const __attribute__((address_space(1))) unsigned int*)g,
        (__attribute__((address_space(3))) unsigned int*)l, 16, 0, 0);
}
static __device__ __forceinline__ void gload_lds4(const void* g, void* l) {
    __builtin_amdgcn_global_load_lds(
        (const __attribute__((address_space(1))) unsigned int*)g,
        (__attribute__((address_space(3))) unsigned int*)l, 4, 0, 0);
}

// ---- K1: codebook -> fp8 frag-permuted units + pre-scaled e_sq ----
// Row r (512 B) = 32 units of 16 B. Logical unit u = p*4+g holds ksteps
// (2p,2p+1) for lane-group g: bytes 0..7 = dims(64p+8g..+7), 8..15 = +32.
// Stored at position (u ^ (r&7)); K2 reads with the same XOR.
__global__ __launch_bounds__(256)
void vq_convert_cb(const float* __restrict__ cb,
                   unsigned char* __restrict__ cbf8,
                   float* __restrict__ esqp)
{
    const int r = blockIdx.x * 8 + (threadIdx.x >> 5);
    const int u = threadIdx.x & 31;
    const int p = u >> 2, g = u & 3;
    const int k0 = p * 64 + g * 8;
    const float* src = cb + (size_t)r * DD;
    float4 a0 = *reinterpret_cast<const float4*>(src + k0);
    float4 a1 = *reinterpret_cast<const float4*>(src + k0 + 4);
    float4 b0 = *reinterpret_cast<const float4*>(src + k0 + 32);
    float4 b1 = *reinterpret_cast<const float4*>(src + k0 + 36);
    unsigned int w0 = pk8<false>(a0.x, a0.y, 0); w0 = pk8<true>(a0.z, a0.w, w0);
    unsigned int w1 = pk8<false>(a1.x, a1.y, 0); w1 = pk8<true>(a1.z, a1.w, w1);
    unsigned int w2 = pk8<false>(b0.x, b0.y, 0); w2 = pk8<true>(b0.z, b0.w, w2);
    unsigned int w3 = pk8<false>(b1.x, b1.y, 0); w3 = pk8<true>(b1.z, b1.w, w3);
    float s2 = a0.x*a0.x + a0.y*a0.y + a0.z*a0.z + a0.w*a0.w
             + a1.x*a1.x + a1.y*a1.y + a1.z*a1.z + a1.w*a1.w
             + b0.x*b0.x + b0.y*b0.y + b0.z*b0.z + b0.w*b0.w
             + b1.x*b1.x + b1.y*b1.y + b1.z*b1.z + b1.w*b1.w;
#pragma unroll
    for (int off = 16; off > 0; off >>= 1) s2 += __shfl_xor(s2, off);
    if (u == 0) esqp[r] = s2 * SC_ESQ;
    uint4 o = {w0, w1, w2, w3};
    *reinterpret_cast<uint4*>(cbf8 + (size_t)r * DD + (u ^ (r & 7)) * 16) = o;
}

// ---- K2: fp8 scan, one octant x 128 q rows per block ----
__global__ __launch_bounds__(256, 4)
void vq_scan_kernel(const float* __restrict__ h,
                    const unsigned char* __restrict__ cbf8,
                    const float* __restrict__ esqp,
                    unsigned int* __restrict__ wlist,
                    unsigned int* __restrict__ wcnt)
{
    __shared__ __align__(16) unsigned char sC[2][KC * DD];   // 32 KB dbuf
    __shared__ __align__(16) float sEsq[2][KC];
    __shared__ int sCnt[BQ];

    const int tid  = threadIdx.x;
    const int w    = tid >> 6;          // wave 0..3, owns q [w*32, w*32+32)
    const int lane = tid & 63;
    const int c16  = lane & 15;
    const int ub   = lane >> 4;
    const int oct  = blockIdx.x & 7;    // constant per XCD -> slice L2-pinned
    const int qt   = blockIdx.x >> 3;
    const int qb   = qt * BQ;
    const int g0   = oct * OCODES;

    if (tid < BQ) sCnt[tid] = NPROT;

    // ---- inline h -> fp8 B-fragments: hf[cg][s], cg = q col-group (2x16) ----
    unsigned long hf[2][16];
#pragma unroll
    for (int cg = 0; cg < 2; ++cg) {
        const size_t qrow = (size_t)(qb + w * 32 + cg * 16 + c16);
#pragma unroll
        for (int s = 0; s < 16; ++s) {
            const float* src = h + qrow * DD + s * 32 + ub * 8;
            float4 x = *reinterpret_cast<const float4*>(src);
            float4 y = *reinterpret_cast<const float4*>(src + 4);
            unsigned int lo = pk8<false>(x.x, x.y, 0); lo = pk8<true>(x.z, x.w, lo);
            unsigned int hi = pk8<false>(y.x, y.y, 0); hi = pk8<true>(y.z, y.w, hi);
            hf[cg][s] = (unsigned long)lo | ((unsigned long)hi << 32);
        }
    }

    float mrun[2] = {-1e38f, -1e38f};
    float b1L[2]  = {-1e38f, -1e38f};
    float b2L[2]  = {-1e38f, -1e38f};
    int   b1C[2]  = {0, 0};
    int   b2C[2]  = {0, 0};

    const int sz = c16 & 7;

    auto stage = [&](int b, int ct) {
        const unsigned char* gc = cbf8 + ((size_t)g0 + (size_t)ct * KC) * DD;
#pragma unroll
        for (int r = 0; r < 4; ++r)
            gload_lds16(gc + r * 4096 + tid * 16, &sC[b][0] + r * 4096 + tid * 16);
        if (w == 0 && lane < KC)
            gload_lds4((const char*)(esqp + g0 + ct * KC) + lane * 4,
                       (char*)&sEsq[b][0] + lane * 4);
    };

    // track only in the main loop (prepass re-scans chunk 0: double-tracking
    // would duplicate chunk-0 tops into b2 -- the round-6 bug).
    auto scan_chunk = [&](int cur, int gbase, bool append, bool track) {
        const float thr0 = mrun[0] - TH2, thr1 = mrun[1] - TH2;
        float ml0 = -1e38f, ml1 = -1e38f;
#pragma unroll 1
        for (int ct = 0; ct < 2; ++ct) {
            const int crow = ct * 16 + c16;
            const unsigned char* base = &sC[cur][crow * DD];
            f32x4 acc0 = {0.f, 0.f, 0.f, 0.f};
            f32x4 acc1 = {0.f, 0.f, 0.f, 0.f};
            u64x2 a[4];
            // batch 0: units p=0..3 (ksteps 0..7)
#pragma unroll
            for (int p = 0; p < 4; ++p)
                a[p] = *reinterpret_cast<const u64x2*>(base + ((p * 4 + ub) ^ sz) * 16);
#pragma unroll
            for (int p = 0; p < 4; ++p) {
                acc0 = mfma8(a[p].x, hf[0][2 * p],     acc0);
                acc1 = mfma8(a[p].x, hf[1][2 * p],     acc1);
                acc0 = mfma8(a[p].y, hf[0][2 * p + 1], acc0);
                acc1 = mfma8(a[p].y, hf[1][2 * p + 1], acc1);
            }
            // batch 1: units p=4..7 (ksteps 8..15)
#pragma unroll
            for (int p = 0; p < 4; ++p)
                a[p] = *reinterpret_cast<const u64x2*>(base + (((p + 4) * 4 + ub) ^ sz) * 16);
#pragma unroll
            for (int p = 0; p < 4; ++p) {
                acc0 = mfma8(a[p].x, hf[0][2 * (p + 4)],     acc0);
                acc1 = mfma8(a[p].x, hf[1][2 * (p + 4)],     acc1);
                acc0 = mfma8(a[p].y, hf[0][2 * (p + 4) + 1], acc0);
                acc1 = mfma8(a[p].y, hf[1][2 * (p + 4) + 1], acc1);
            }
            f32x4 ep = *reinterpret_cast<const f32x4*>(&sEsq[cur][ct * 16 + ub * 4]);
            float Lv0[4], Lv1[4];
#pragma unroll
            for (int r = 0; r < 4; ++r) {
                Lv0[r] = fmaf(acc0[r], SC_CROSS, -ep[r]);
                Lv1[r] = fmaf(acc1[r], SC_CROSS, -ep[r]);
            }
            if (track) {
#pragma unroll
                for (int r = 0; r < 4; ++r) {
                    const int cd = gbase + ct * 16 + ub * 4 + r;
                    if (Lv0[r] > b1L[0])      { b2L[0] = b1L[0]; b2C[0] = b1C[0];
                                                b1L[0] = Lv0[r]; b1C[0] = cd; }
                    else if (Lv0[r] > b2L[0]) { b2L[0] = Lv0[r]; b2C[0] = cd; }
                    if (Lv1[r] > b1L[1])      { b2L[1] = b1L[1]; b2C[1] = b1C[1];
                                                b1L[1] = Lv1[r]; b1C[1] = cd; }
                    else if (Lv1[r] > b2L[1]) { b2L[1] = Lv1[r]; b2C[1] = cd; }
                }
            }
            if (append) {
                if (Lv0[0] > thr0 || Lv0[1] > thr0 || Lv0[2] > thr0 || Lv0[3] > thr0) {
                    const int rowloc = w * 32 + c16;
                    const size_t lb = ((size_t)(qb + rowloc) * NSUB + oct) * CAPS;
#pragma unroll
                    for (int r = 0; r < 4; ++r)
                        if (Lv0[r] > thr0) {
                            int idx  = atomicAdd(&sCnt[rowloc], 1);
                            int slot = idx < CAPS ? idx
                                     : NPROT + ((idx - NPROT) & (NPROT - 1));
                            wlist[lb + slot] = packE(Lv0[r], gbase + ct * 16 + ub * 4 + r);
                        }
                }
                if (Lv1[0] > thr1 || Lv1[1] > thr1 || Lv1[2] > thr1 || Lv1[3] > thr1) {
                    const int rowloc = w * 32 + 16 + c16;
                    const size_t lb = ((size_t)(qb + rowloc) * NSUB + oct) * CAPS;
#pragma unroll
                    for (int r = 0; r < 4; ++r)
                        if (Lv1[r] > thr1) {
                            int idx  = atomicAdd(&sCnt[rowloc], 1);
                            int slot = idx < CAPS ? idx
                                     : NPROT + ((idx - NPROT) & (NPROT - 1));
                            wlist[lb + slot] = packE(Lv1[r], gbase + ct * 16 + ub * 4 + r);
                        }
                }
            }
            ml0 = fmaxf(ml0, fmaxf(fmaxf(Lv0[0], Lv0[1]), fmaxf(Lv0[2], Lv0[3])));
            ml1 = fmaxf(ml1, fmaxf(fmaxf(Lv1[0], Lv1[1]), fmaxf(Lv1[2], Lv1[3])));
        }
        ml0 = fmaxf(ml0, __shfl_xor(ml0, 16)); ml0 = fmaxf(ml0, __shfl_xor(ml0, 32));
        ml1 = fmaxf(ml1, __shfl_xor(ml1, 16)); ml1 = fmaxf(ml1, __shfl_xor(ml1, 32));
        mrun[0] = fmaxf(mrun[0], ml0);
        mrun[1] = fmaxf(mrun[1], ml1);
    };

    // prologue: stage chunk 0; prime running max (no append, no tracking)
    stage(0, 0);
    __syncthreads();
    scan_chunk(0, g0, false, false);

    int cur = 0;
    for (int t = 0; t < NCHUNK; ++t) {
        if (t + 1 < NCHUNK) stage(cur ^ 1, t + 1);
        scan_chunk(cur, g0 + t * KC, true, true);
        __syncthreads();
        cur ^= 1;
    }

    // protected slots: per cg row, owning lane ub writes its top-2
#pragma unroll
    for (int cg = 0; cg < 2; ++cg) {
        const int rowloc = w * 32 + cg * 16 + c16;
        const size_t lb = ((size_t)(qb + rowloc) * NSUB + oct) * CAPS;
        wlist[lb + ub * 2]     = packE(b1L[cg], b1C[cg]);
        wlist[lb + ub * 2 + 1] = packE(b2L[cg], b2C[cg]);
    }
    if (tid < BQ) wcnt[(size_t)(qb + tid) * NSUB + oct] = (unsigned)sCnt[tid];
}

// ---- K3: merge sub-lists, dedup, prune, exact fp32 softmax gather ----
__global__ __launch_bounds__(512)
void vq_merge_kernel(const float* __restrict__ h,
                     const float* __restrict__ cb,
                     const unsigned int* __restrict__ wlist,
                     const unsigned int* __restrict__ wcnt,
                     float* __restrict__ out)
{
    const int w    = threadIdx.x >> 6;
    const int lane = threadIdx.x & 63;
    const int qg   = blockIdx.x * 8 + w;

    const int sl = lane >> 3;           // sub-list (octant) 0..7
    const int s0 = (lane & 7) * 2;      // slot pair
    const size_t base = ((size_t)qg * NSUB + sl) * CAPS;
    const unsigned cnt   = wcnt[(size_t)qg * NSUB + sl];
    const unsigned limit = cnt < (unsigned)CAPS ? cnt : (unsigned)CAPS;

    uint2 e2 = *reinterpret_cast<const uint2*>(&wlist[base + s0]);
    int   code0 = e2.x & 0xFFFF, code1 = e2.y & 0xFFFF;
    float L0 = __uint_as_float(e2.x & 0xFFFF0000u);
    float L1 = __uint_as_float(e2.y & 0xFFFF0000u);
    bool v0 = (unsigned)s0 < limit;
    bool v1 = (unsigned)(s0 + 1) < limit;
    {
        uint4 p0 = *reinterpret_cast<const uint4*>(&wlist[base]);
        uint4 p1 = *reinterpret_cast<const uint4*>(&wlist[base + 4]);
        const unsigned pc[8] = {p0.x & 0xFFFFu, p0.y & 0xFFFFu, p0.z & 0xFFFFu, p0.w & 0xFFFFu,
                                p1.x & 0xFFFFu, p1.y & 0xFFFFu, p1.z & 0xFFFFu, p1.w & 0xFFFFu};
        const int lim0 = (s0 >= NPROT) ? 8 : s0;
        bool d0 = false, d1 = false;
#pragma unroll
        for (int j = 0; j < 8; ++j) {
            d0 |= (j < lim0) && ((unsigned)code0 == pc[j]);
            d1 |= (j < lim0) && ((unsigned)code1 == pc[j]);
        }
        d1 |= (code1 == code0) && (s0 < NPROT);
        v0 &= !d0; v1 &= !d1;
    }

    float m = fmaxf(v0 ? L0 : -1e38f, v1 ? L1 : -1e38f);
#pragma unroll
    for (int off = 1; off < 64; off <<= 1) m = fmaxf(m, __shfl_xor(m, off));
    const float thr = m - PRUNE;
    unsigned long long mask0 = __ballot(v0 && L0 > thr);
    unsigned long long mask1 = __ballot(v1 && L1 > thr);

    float hreg[8];
    const float* hp = h + (size_t)qg * DD + lane * 8;
#pragma unroll
    for (int j = 0; j < 8; ++j) hreg[j] = hp[j];

    float Mex = -1e38f, lsum = 0.f;
    float acc[8] = {0.f,0.f,0.f,0.f,0.f,0.f,0.f,0.f};

    auto process = [&](unsigned long long mask, int codev) {
#pragma unroll 1
        while (mask) {
            const int s = __builtin_ctzll(mask);
            mask &= mask - 1;
            const int code = __shfl(codev, s);
            const float* cp = cb + (size_t)code * DD + lane * 8;
            float c[8];
            float dot = 0.f, s2 = 0.f;
#pragma unroll
            for (int j = 0; j < 8; ++j) {
                c[j] = cp[j];
                dot += hreg[j] * c[j];
                s2  += c[j] * c[j];
            }
#pragma unroll
            for (int off = 32; off > 0; off >>= 1) {
                dot += __shfl_xor(dot, off);
                s2  += __shfl_xor(s2,  off);
            }
            const float Lex = dot * SC_CROSS - s2 * SC_ESQ;   // exact log2-logit
            const float mn  = fmaxf(Mex, Lex);
            const float f   = exp2f(Mex - mn);
            const float wj  = exp2f(Lex - mn);
            lsum = lsum * f + wj;
#pragma unroll
            for (int j = 0; j < 8; ++j) acc[j] = acc[j] * f + wj * c[j];
            Mex = mn;
        }
    };
    process(mask0, code0);
    process(mask1, code1);

    const float inv = 1.0f / lsum;
    float* op = out + (size_t)qg * DD + lane * 8;
    float4 o0 = {acc[0]*inv, acc[1]*inv, acc[2]*inv, acc[3]*inv};
    float4 o1 = {acc[4]*inv, acc[5]*inv, acc[6]*inv, acc[7]*inv};
    *reinterpret_cast<float4*>(op)     = o0;
    *reinterpret_cast<float4*>(op + 4) = o1;
}

extern "C" void kernel_launch(void* const* d_in, const int* in_sizes, int n_in,
                              void* d_out, int out_size, void* d_ws, size_t ws_size,
                              hipStream_t stream) {
    const float* h  = (const float*)d_in[0];   // (16384, 512) fp32
    const float* cb = (const float*)d_in[1];   // (8192, 512) fp32
    float* out = (float*)d_out;                // (16384, 512) fp32

    // ws: cbf8 4MB | esqp 32KB | wlist 8.4MB | wcnt 512KB  (~12.9 MB)
    char* p = (char*)d_ws;
    unsigned char* cbf8 = (unsigned char*)p;  p += SZ_CBF8;
    float*         esqp = (float*)p;          p += SZ_ESQ;
    unsigned int*  wlist = (unsigned int*)p;  p += SZ_WLIST;
    unsigned int*  wcnt  = (unsigned int*)p;

    vq_convert_cb<<<dim3(NCODES / 8), dim3(256), 0, stream>>>(cb, cbf8, esqp);
    vq_scan_kernel<<<dim3(1024), dim3(256), 0, stream>>>(h, cbf8, esqp, wlist, wcnt);
    vq_merge_kernel<<<dim3(16384 / 8), dim3(512), 0, stream>>>(h, cb, wlist, wcnt, out);
}